// Round 7
// baseline (174.943 us; speedup 1.0000x reference)
//
#include <hip/hip_runtime.h>
#include <hip/hip_bf16.h>

#define BB 8
#define NN 2048
#define FF 128
#define RB 32
#define MT 128

typedef short bh8 __attribute__((ext_vector_type(8)));
typedef float fl4 __attribute__((ext_vector_type(4)));
typedef unsigned short u16;
typedef unsigned long long u64;
typedef union { bh8 v; unsigned u[4]; } bh8u;

__device__ __forceinline__ u16 f2bf(float x) {
    unsigned u = __float_as_uint(x);
    return (u16)((u + 0x7FFFu + ((u >> 16) & 1u)) >> 16);
}

__device__ __forceinline__ void loadB(bh8 (&buf)[8], const u16* hB, int lr, int kbase) {
    #pragma unroll
    for (int ct = 0; ct < 8; ++ct)
        buf[ct] = *(const bh8*)(hB + (ct * 16 + lr) * NN + kbase);
}

__device__ __forceinline__ void mfma16(bh8 a0, bh8 a1, const bh8 (&buf)[8],
                                       fl4 (&c0)[8], fl4 (&c1)[8]) {
    #pragma unroll
    for (int ct = 0; ct < 8; ++ct) {
        c0[ct] = __builtin_amdgcn_mfma_f32_16x16x32_bf16(a0, buf[ct], c0[ct], 0, 0, 0);
        c1[ct] = __builtin_amdgcn_mfma_f32_16x16x32_bf16(a1, buf[ct], c1[ct], 0, 0, 0);
    }
}

// ---------------------------------------------------------------------------
// kernel 1 (fused): h = feat@W + b -> htg bf16 transposed [b][o][n];
// esrc; eed = exp(edst), eed2 = exp(0.01*edst); gmax via monotone-u32 atomic;
// adjacency bit-pack (rides the mandatory 134 MB adj stream).
// ---------------------------------------------------------------------------
__global__ __launch_bounds__(256) void k_hp(
    const float* __restrict__ feat, const int* __restrict__ adj,
    const float* __restrict__ W, const float* __restrict__ bias,
    const float* __restrict__ a, u16* __restrict__ htg,
    float* __restrict__ esrc, float* __restrict__ eed, float* __restrict__ eed2,
    unsigned* __restrict__ gmaxu, u64* __restrict__ bm)
{
    __shared__ float fsh[8][FF];
    __shared__ float red[2][2][8];
    const int t = threadIdx.x;
    const long row0 = (long)blockIdx.x * 8;

    ((float4*)&fsh[0][0])[t] = ((const float4*)(feat + row0 * FF))[t];
    __syncthreads();

    const int o = t & 127;
    const int half = t >> 7;
    float acc[4] = {0.f, 0.f, 0.f, 0.f};
    #pragma unroll 4
    for (int k = 0; k < FF; ++k) {
        const float w = W[k * FF + o];
        #pragma unroll
        for (int r = 0; r < 4; ++r)
            acc[r] = fmaf(fsh[half * 4 + r][k], w, acc[r]);
    }
    const float bo = bias[o];
    const float as = a[o];
    const float ad = a[FF + o];
    float ps[4], pd[4];
    #pragma unroll
    for (int r = 0; r < 4; ++r) {
        acc[r] += bo;
        ps[r] = acc[r] * as;
        pd[r] = acc[r] * ad;
    }
    {
        const int bI = (int)(row0 >> 11);
        const int nloc = (int)(row0 & 2047) + half * 4;
        ushort4 hv;
        hv.x = f2bf(acc[0]); hv.y = f2bf(acc[1]);
        hv.z = f2bf(acc[2]); hv.w = f2bf(acc[3]);
        *(ushort4*)&htg[((long)bI * FF + o) * NN + nloc] = hv;
    }
    #pragma unroll
    for (int r = 0; r < 4; ++r) {
        #pragma unroll
        for (int off = 32; off > 0; off >>= 1) {
            ps[r] += __shfl_down(ps[r], off, 64);
            pd[r] += __shfl_down(pd[r], off, 64);
        }
    }
    const int wv = (t >> 6) & 1;
    if ((t & 63) == 0) {
        #pragma unroll
        for (int r = 0; r < 4; ++r) {
            red[half][wv][r]     = ps[r];
            red[half][wv][4 + r] = pd[r];
        }
    }
    __syncthreads();
    if (t < 16) {
        const int hh = t >> 3, idx = t & 7;
        const float v = red[hh][0][idx] + red[hh][1][idx];
        const long row = row0 + hh * 4 + (idx & 3);
        if (idx < 4) {
            esrc[row] = v;
        } else {
            eed[row]  = __expf(v);
            eed2[row] = __expf(0.01f * v);
        }
        // gmax over this block's 8 edst values (lanes idx>=4) -> 1 atomic
        float mv = (idx >= 4) ? v : -3.4e38f;
        #pragma unroll
        for (int off = 8; off > 0; off >>= 1)
            mv = fmaxf(mv, __shfl_xor(mv, off, 16));
        if (t == 0) {
            unsigned bu = __float_as_uint(mv);
            bu = (bu & 0x80000000u) ? ~bu : (bu | 0x80000000u);
            atomicMax(gmaxu + (int)(row0 >> 11), bu);
        }
    }

    // ---- pack tail: wave w2 packs rows 2*w2, 2*w2+1 (32 chunks of 64 cols)
    {
        const int w2 = t >> 6, lane = t & 63;
        #pragma unroll 8
        for (int i = 0; i < 64; ++i) {
            const int row = 2 * w2 + (i >> 5);
            const int chunk = i & 31;
            const int av = adj[(row0 + row) * NN + chunk * 64 + lane];
            const u64 m64 = __ballot(av > 0);
            if (lane == 0) bm[(row0 + row) * 32 + chunk] = m64;
        }
    }
}

// ---------------------------------------------------------------------------
// kernel 2: block = 32 rows, 4 waves, m-split 4 (wave w owns windows w+4it).
// P built in registers from bitmask + precomputed exp tables (NO trans in
// main loop). B-fragments: 3 rotating reg buffers, each reloaded 3 slots
// ahead of use, sched_barrier(0)-pinned per slot. 3-phase LDS reduce (34KB).
// ---------------------------------------------------------------------------
__global__ __launch_bounds__(256, 2) void k_attn(
    const u64* __restrict__ bm, const float* __restrict__ mask,
    const u16* __restrict__ htg, const float* __restrict__ esrc,
    const float* __restrict__ eed, const float* __restrict__ eed2,
    const unsigned* __restrict__ gmaxu, float* __restrict__ out)
{
    __shared__ float accbuf[2][RB][FF + 4];   // 33.8 KB
    __shared__ float psum_sh[4][RB];

    const int t = threadIdx.x;
    const int b = blockIdx.x & 7;               // batch -> XCD affinity
    const int n0 = (blockIdx.x >> 3) * RB;
    const int w = t >> 6, lane = t & 63;
    const int lr = lane & 15, g = lane >> 4;

    const unsigned gu = gmaxu[b];
    const float gm = __uint_as_float((gu & 0x80000000u) ? (gu & 0x7FFFFFFFu) : ~gu);
    const float es0 = esrc[b * NN + n0 + lr];
    const float es1 = esrc[b * NN + n0 + 16 + lr];
    const float m0t = es0 + gm; const float M0 = fmaxf(m0t, 0.01f * m0t);
    const float m1t = es1 + gm; const float M1 = fmaxf(m1t, 0.01f * m1t);
    // exp(leaky(es+ed)-M) = (ed >= -es) ? A*exp(ed) : Bv*exp(0.01 ed)
    const float A0 = __expf(es0 - M0), Bv0 = __expf(0.01f * es0 - M0), T0 = __expf(-es0);
    const float A1 = __expf(es1 - M1), Bv1 = __expf(0.01f * es1 - M1), T1 = __expf(-es1);

    const uint4* bmb = (const uint4*)(bm + ((long)b * NN + n0) * 32);
    const float* eeb  = eed  + b * NN;
    const float* ee2b = eed2 + b * NN;
    const u16* hB = htg + (long)b * FF * NN;

    fl4 acc0[8], acc1[8];
    #pragma unroll
    for (int ct = 0; ct < 8; ++ct) {
        acc0[ct] = (fl4){0.f, 0.f, 0.f, 0.f};
        acc1[ct] = (fl4){0.f, 0.f, 0.f, 0.f};
    }
    float psum0 = 0.f, psum1 = 0.f;

    // prologue: 3-deep B-frag pipeline (chunks 0,1,2)
    bh8 bf0[8], bf1[8], bf2[8];
    loadB(bf0, hB, lr, w * MT + g * 8);
    loadB(bf1, hB, lr, w * MT + g * 8 + 32);
    loadB(bf2, hB, lr, w * MT + g * 8 + 64);

    #pragma unroll
    for (int it = 0; it < 4; ++it) {
        const int kb = (w + 4 * it) * MT + g * 8;
        const uint4 bq0 = bmb[lr * 16 + (w + 4 * it)];
        const uint4 bq1 = bmb[(16 + lr) * 16 + (w + 4 * it)];

        bh8 af0[4], af1[4];
        float pst0 = 0.f, pst1 = 0.f;
        #pragma unroll
        for (int kc = 0; kc < 4; ++kc) {
            const unsigned q0 = (kc == 0) ? bq0.x : (kc == 1) ? bq0.y : (kc == 2) ? bq0.z : bq0.w;
            const unsigned q1 = (kc == 0) ? bq1.x : (kc == 1) ? bq1.y : (kc == 2) ? bq1.z : bq1.w;
            const unsigned by0 = (q0 >> (8 * g)) & 0xFFu;
            const unsigned by1 = (q1 >> (8 * g)) & 0xFFu;
            const float4 Ea = *(const float4*)(eeb + kb + kc * 32);
            const float4 Eb = *(const float4*)(eeb + kb + kc * 32 + 4);
            const float4 Fa = *(const float4*)(ee2b + kb + kc * 32);
            const float4 Fb = *(const float4*)(ee2b + kb + kc * 32 + 4);
            const float pe[8] = {Ea.x, Ea.y, Ea.z, Ea.w, Eb.x, Eb.y, Eb.z, Eb.w};
            const float pf[8] = {Fa.x, Fa.y, Fa.z, Fa.w, Fb.x, Fb.y, Fb.z, Fb.w};
            bh8u pa, pb;
            float s00 = 0.f, s01 = 0.f, s10 = 0.f, s11 = 0.f;
            #pragma unroll
            for (int jj = 0; jj < 4; ++jj) {
                const int j0 = 2 * jj, j1 = 2 * jj + 1;
                const float v00 = ((by0 >> j0) & 1u) ? ((pe[j0] >= T0) ? A0 * pe[j0] : Bv0 * pf[j0]) : 0.f;
                const float v01 = ((by0 >> j1) & 1u) ? ((pe[j1] >= T0) ? A0 * pe[j1] : Bv0 * pf[j1]) : 0.f;
                const float v10 = ((by1 >> j0) & 1u) ? ((pe[j0] >= T1) ? A1 * pe[j0] : Bv1 * pf[j0]) : 0.f;
                const float v11 = ((by1 >> j1) & 1u) ? ((pe[j1] >= T1) ? A1 * pe[j1] : Bv1 * pf[j1]) : 0.f;
                float2 c0f; c0f.x = v00; c0f.y = v01;
                float2 c1f; c1f.x = v10; c1f.y = v11;
                __hip_bfloat162 r0 = __float22bfloat162_rn(c0f);
                __hip_bfloat162 r1 = __float22bfloat162_rn(c1f);
                const unsigned u0 = *reinterpret_cast<unsigned*>(&r0);
                const unsigned u1 = *reinterpret_cast<unsigned*>(&r1);
                pa.u[jj] = u0;
                pb.u[jj] = u1;
                // psum accumulates the ROUNDED values (num/denom consistent)
                s00 += __uint_as_float(u0 << 16);
                s01 += __uint_as_float(u0 & 0xFFFF0000u);
                s10 += __uint_as_float(u1 << 16);
                s11 += __uint_as_float(u1 & 0xFFFF0000u);
            }
            pst0 += s00 + s01;
            pst1 += s10 + s11;
            af0[kc] = pa.v;
            af1[kc] = pb.v;
        }
        psum0 += pst0;
        psum1 += pst1;
        __builtin_amdgcn_sched_barrier(0);

        // 4 slots: MFMA on buf (c%3), then reload same buf with chunk c+3
        #pragma unroll
        for (int kc = 0; kc < 4; ++kc) {
            const int c = it * 4 + kc;
            bh8 (&cur)[8] = (c % 3 == 0) ? bf0 : ((c % 3 == 1) ? bf1 : bf2);
            mfma16(af0[kc], af1[kc], cur, acc0, acc1);
            if (c + 3 < 16) {
                const int cn = c + 3;
                loadB(cur, hB, lr, (w + 4 * (cn >> 2)) * MT + g * 8 + (cn & 3) * 32);
            }
            __builtin_amdgcn_sched_barrier(0);
        }
    }

    // psum: partials for rows lr / 16+lr live in lanes {lr, lr+16, lr+32, lr+48}
    psum0 += __shfl_xor(psum0, 16, 64);
    psum0 += __shfl_xor(psum0, 32, 64);
    psum1 += __shfl_xor(psum1, 16, 64);
    psum1 += __shfl_xor(psum1, 32, 64);
    if (lane < 16) {
        psum_sh[w][lr] = psum0;
        psum_sh[w][16 + lr] = psum1;
    }

    // 3-phase partial reduce. C/D layout: col=ct*16+lr, row=g*4+reg [m89/m91]
    if (w >= 2) {
        #pragma unroll
        for (int ct = 0; ct < 8; ++ct)
            #pragma unroll
            for (int reg = 0; reg < 4; ++reg) {
                accbuf[w - 2][g * 4 + reg][ct * 16 + lr]      = acc0[ct][reg];
                accbuf[w - 2][16 + g * 4 + reg][ct * 16 + lr] = acc1[ct][reg];
            }
    }
    __syncthreads();
    if (w < 2) {
        #pragma unroll
        for (int ct = 0; ct < 8; ++ct)
            #pragma unroll
            for (int reg = 0; reg < 4; ++reg) {
                acc0[ct][reg] += accbuf[w][g * 4 + reg][ct * 16 + lr];
                acc1[ct][reg] += accbuf[w][16 + g * 4 + reg][ct * 16 + lr];
            }
        if (w == 1) {
            #pragma unroll
            for (int ct = 0; ct < 8; ++ct)
                #pragma unroll
                for (int reg = 0; reg < 4; ++reg) {
                    accbuf[1][g * 4 + reg][ct * 16 + lr]      = acc0[ct][reg];
                    accbuf[1][16 + g * 4 + reg][ct * 16 + lr] = acc1[ct][reg];
                }
        }
    }
    __syncthreads();
    if (w == 0) {
        const long obase = ((long)b * NN + n0) * FF;
        #pragma unroll
        for (int reg = 0; reg < 4; ++reg) {
            const int r0 = g * 4 + reg;
            const int r1 = 16 + r0;
            const float pt0 = psum_sh[0][r0] + psum_sh[1][r0] + psum_sh[2][r0] + psum_sh[3][r0];
            const float pt1 = psum_sh[0][r1] + psum_sh[1][r1] + psum_sh[2][r1] + psum_sh[3][r1];
            const float sc0 = mask[b * NN + n0 + r0] / pt0;
            const float sc1 = mask[b * NN + n0 + r1] / pt1;
            #pragma unroll
            for (int ct = 0; ct < 8; ++ct) {
                out[obase + (long)r0 * FF + ct * 16 + lr] =
                    (acc0[ct][reg] + accbuf[1][r0][ct * 16 + lr]) * sc0;
                out[obase + (long)r1 * FF + ct * 16 + lr] =
                    (acc1[ct][reg] + accbuf[1][r1][ct * 16 + lr]) * sc1;
            }
        }
    }
}

// ---------------------------------------------------------------------------
extern "C" void kernel_launch(void* const* d_in, const int* in_sizes, int n_in,
                              void* d_out, int out_size, void* d_ws, size_t ws_size,
                              hipStream_t stream)
{
    const float* feat = (const float*)d_in[0];
    const int*   adj  = (const int*)d_in[1];
    const float* mask = (const float*)d_in[2];
    const float* W    = (const float*)d_in[3];
    const float* bias = (const float*)d_in[4];
    const float* a    = (const float*)d_in[5];
    float* out = (float*)d_out;

    // ws: htg bf16 [8][128][2048] | esrc | eed | eed2 (f32 16K each) | gmaxu | bm
    u16*      htg   = (u16*)d_ws;
    float*    esrc  = (float*)(htg + (size_t)BB * FF * NN);
    float*    eed   = esrc + BB * NN;
    float*    eed2  = eed + BB * NN;
    unsigned* gmaxu = (unsigned*)(eed2 + BB * NN);
    u64*      bmp   = (u64*)(gmaxu + 8);

    hipMemsetAsync(gmaxu, 0, BB * sizeof(unsigned), stream);
    k_hp  <<<BB * NN / 8, 256, 0, stream>>>(feat, adj, W, bias, a, htg, esrc, eed, eed2, gmaxu, bmp);
    k_attn<<<BB * (NN / RB), 256, 0, stream>>>(bmp, mask, htg, esrc, eed, eed2, gmaxu, out);
}

// Round 8
// 92.037 us; speedup vs baseline: 1.9008x; 1.9008x over previous
//
#include <hip/hip_runtime.h>
#include <hip/hip_bf16.h>

#define BB 8
#define NN 2048
#define FF 128
#define RB 32
#define MT 128

typedef short bh8 __attribute__((ext_vector_type(8)));
typedef float fl4 __attribute__((ext_vector_type(4)));
typedef unsigned short u16;
typedef unsigned long long u64;
typedef union { bh8 v; unsigned u[4]; } bh8u;

__device__ __forceinline__ u16 f2bf(float x) {
    unsigned u = __float_as_uint(x);
    return (u16)((u + 0x7FFFu + ((u >> 16) & 1u)) >> 16);
}

__device__ __forceinline__ void loadB(bh8 (&buf)[8], const u16* hB, int lr, int kbase) {
    #pragma unroll
    for (int ct = 0; ct < 8; ++ct)
        buf[ct] = *(const bh8*)(hB + (ct * 16 + lr) * NN + kbase);
}

// ---------------------------------------------------------------------------
// kernel 1: ballot-free adjacency bit-pack. Thread t packs ints [64t,64t+64)
// via 16 independent int4 loads -> nibble trick -> one coalesced u64 store.
// Pure HBM stream, no cross-lane ops, no serial chains.
// ---------------------------------------------------------------------------
__global__ __launch_bounds__(256) void k_pack(
    const int* __restrict__ adj, u64* __restrict__ bm)
{
    const long gt = (long)blockIdx.x * 256 + threadIdx.x;   // u64 index
    const int4* src = (const int4*)adj + gt * 16;
    u64 m = 0;
    #pragma unroll
    for (int i = 0; i < 16; ++i) {
        const int4 v = src[i];
        const unsigned nib = (v.x > 0 ? 1u : 0u) | (v.y > 0 ? 2u : 0u)
                           | (v.z > 0 ? 4u : 0u) | (v.w > 0 ? 8u : 0u);
        m |= (u64)nib << (4 * i);
    }
    bm[gt] = m;
}

// ---------------------------------------------------------------------------
// kernel 2: h = feat @ W + b -> htg bf16 transposed [b][o][n]; side outputs
// esrc, edst, eed = exp(edst), eed2 = exp(0.01*edst).
// ---------------------------------------------------------------------------
__global__ __launch_bounds__(256) void k_h(
    const float* __restrict__ feat, const float* __restrict__ W,
    const float* __restrict__ bias, const float* __restrict__ a,
    u16* __restrict__ htg, float* __restrict__ esrc, float* __restrict__ edst,
    float* __restrict__ eed, float* __restrict__ eed2)
{
    __shared__ float fsh[8][FF];
    __shared__ float red[2][2][8];
    const int t = threadIdx.x;
    const long row0 = (long)blockIdx.x * 8;

    ((float4*)&fsh[0][0])[t] = ((const float4*)(feat + row0 * FF))[t];
    __syncthreads();

    const int o = t & 127;
    const int half = t >> 7;
    float acc[4] = {0.f, 0.f, 0.f, 0.f};
    #pragma unroll 4
    for (int k = 0; k < FF; ++k) {
        const float w = W[k * FF + o];
        #pragma unroll
        for (int r = 0; r < 4; ++r)
            acc[r] = fmaf(fsh[half * 4 + r][k], w, acc[r]);
    }
    const float bo = bias[o];
    const float as = a[o];
    const float ad = a[FF + o];
    float ps[4], pd[4];
    #pragma unroll
    for (int r = 0; r < 4; ++r) {
        acc[r] += bo;
        ps[r] = acc[r] * as;
        pd[r] = acc[r] * ad;
    }
    {
        const int bI = (int)(row0 >> 11);
        const int nloc = (int)(row0 & 2047) + half * 4;
        ushort4 hv;
        hv.x = f2bf(acc[0]); hv.y = f2bf(acc[1]);
        hv.z = f2bf(acc[2]); hv.w = f2bf(acc[3]);
        *(ushort4*)&htg[((long)bI * FF + o) * NN + nloc] = hv;
    }
    #pragma unroll
    for (int r = 0; r < 4; ++r) {
        #pragma unroll
        for (int off = 32; off > 0; off >>= 1) {
            ps[r] += __shfl_down(ps[r], off, 64);
            pd[r] += __shfl_down(pd[r], off, 64);
        }
    }
    const int wv = (t >> 6) & 1;
    if ((t & 63) == 0) {
        #pragma unroll
        for (int r = 0; r < 4; ++r) {
            red[half][wv][r]     = ps[r];
            red[half][wv][4 + r] = pd[r];
        }
    }
    __syncthreads();
    if (t < 16) {
        const int hh = t >> 3, idx = t & 7;
        const float v = red[hh][0][idx] + red[hh][1][idx];
        const long row = row0 + hh * 4 + (idx & 3);
        if (idx < 4) {
            esrc[row] = v;
        } else {
            edst[row] = v;
            eed[row]  = __expf(v);
            eed2[row] = __expf(0.01f * v);
        }
    }
}

// ---------------------------------------------------------------------------
// kernel 3: block = 32 rows, 4 waves, m-split 4 (wave w owns windows w+4it).
// P built in registers from bitmask + exp tables (NO transcendentals in the
// main loop): exp(leaky(es+ed)-M) = (E>=T) ? A*E : Bv*F with E=exp(ed),
// F=exp(0.01 ed). B-fragments double-buffered one kc ahead. Final LDS reduce.
// ---------------------------------------------------------------------------
__global__ __launch_bounds__(256, 2) void k_attn(
    const u64* __restrict__ bm, const float* __restrict__ mask,
    const u16* __restrict__ htg, const float* __restrict__ esrc,
    const float* __restrict__ edst, const float* __restrict__ eed,
    const float* __restrict__ eed2, float* __restrict__ out)
{
    __shared__ float accbuf[4][RB][FF + 4];   // ~67.6 KB
    __shared__ float psum_sh[4][RB];

    const int t = threadIdx.x;
    const int b = blockIdx.x & 7;               // batch -> XCD affinity
    const int n0 = (blockIdx.x >> 3) * RB;
    const int w = t >> 6, lane = t & 63;
    const int lr = lane & 15, g = lane >> 4;

    // per-wave gmax over edst[b][:] (8 KB, L2-hot)
    float gmx = -3.4e38f;
    {
        const float4* edp = (const float4*)(edst + b * NN);
        #pragma unroll
        for (int i = 0; i < 8; ++i) {
            const float4 v = edp[lane + 64 * i];
            gmx = fmaxf(gmx, fmaxf(fmaxf(v.x, v.y), fmaxf(v.z, v.w)));
        }
        #pragma unroll
        for (int off = 32; off > 0; off >>= 1)
            gmx = fmaxf(gmx, __shfl_xor(gmx, off, 64));
    }

    const float es0 = esrc[b * NN + n0 + lr];
    const float es1 = esrc[b * NN + n0 + 16 + lr];
    const float m0t = es0 + gmx; const float M0 = fmaxf(m0t, 0.01f * m0t);
    const float m1t = es1 + gmx; const float M1 = fmaxf(m1t, 0.01f * m1t);
    const float A0 = __expf(es0 - M0), Bv0 = __expf(0.01f * es0 - M0), T0 = __expf(-es0);
    const float A1 = __expf(es1 - M1), Bv1 = __expf(0.01f * es1 - M1), T1 = __expf(-es1);

    const uint4* bmb = (const uint4*)(bm + ((long)b * NN + n0) * 32);
    const float* eeb  = eed  + b * NN;
    const float* ee2b = eed2 + b * NN;
    const u16* hB = htg + (long)b * FF * NN;

    fl4 acc0[8], acc1[8];
    #pragma unroll
    for (int ct = 0; ct < 8; ++ct) {
        acc0[ct] = (fl4){0.f, 0.f, 0.f, 0.f};
        acc1[ct] = (fl4){0.f, 0.f, 0.f, 0.f};
    }
    float psum0 = 0.f, psum1 = 0.f;

    #pragma unroll 1
    for (int it = 0; it < 4; ++it) {
        const int kb = (w + 4 * it) * MT + g * 8;
        const uint4 bq0 = bmb[lr * 16 + (w + 4 * it)];
        const uint4 bq1 = bmb[(16 + lr) * 16 + (w + 4 * it)];

        // B-fragments for kc=0
        bh8 bfA[8];
        loadB(bfA, hB, lr, kb);

        // build A-fragments from bitmask + tables
        bh8 af0[4], af1[4];
        #pragma unroll
        for (int kc = 0; kc < 4; ++kc) {
            const unsigned q0 = (kc == 0) ? bq0.x : (kc == 1) ? bq0.y : (kc == 2) ? bq0.z : bq0.w;
            const unsigned q1 = (kc == 0) ? bq1.x : (kc == 1) ? bq1.y : (kc == 2) ? bq1.z : bq1.w;
            const unsigned by0 = (q0 >> (8 * g)) & 0xFFu;
            const unsigned by1 = (q1 >> (8 * g)) & 0xFFu;
            const float4 Ea = *(const float4*)(eeb + kb + kc * 32);
            const float4 Eb = *(const float4*)(eeb + kb + kc * 32 + 4);
            const float4 Fa = *(const float4*)(ee2b + kb + kc * 32);
            const float4 Fb = *(const float4*)(ee2b + kb + kc * 32 + 4);
            const float pe[8] = {Ea.x, Ea.y, Ea.z, Ea.w, Eb.x, Eb.y, Eb.z, Eb.w};
            const float pf[8] = {Fa.x, Fa.y, Fa.z, Fa.w, Fb.x, Fb.y, Fb.z, Fb.w};
            bh8u pa, pb;
            float s0 = 0.f, s1 = 0.f;
            #pragma unroll
            for (int jj = 0; jj < 4; ++jj) {
                const int j0 = 2 * jj, j1 = 2 * jj + 1;
                const float v00 = ((by0 >> j0) & 1u) ? ((pe[j0] >= T0) ? A0 * pe[j0] : Bv0 * pf[j0]) : 0.f;
                const float v01 = ((by0 >> j1) & 1u) ? ((pe[j1] >= T0) ? A0 * pe[j1] : Bv0 * pf[j1]) : 0.f;
                const float v10 = ((by1 >> j0) & 1u) ? ((pe[j0] >= T1) ? A1 * pe[j0] : Bv1 * pf[j0]) : 0.f;
                const float v11 = ((by1 >> j1) & 1u) ? ((pe[j1] >= T1) ? A1 * pe[j1] : Bv1 * pf[j1]) : 0.f;
                float2 c0f; c0f.x = v00; c0f.y = v01;
                float2 c1f; c1f.x = v10; c1f.y = v11;
                __hip_bfloat162 r0 = __float22bfloat162_rn(c0f);
                __hip_bfloat162 r1 = __float22bfloat162_rn(c1f);
                const unsigned u0 = *reinterpret_cast<unsigned*>(&r0);
                const unsigned u1 = *reinterpret_cast<unsigned*>(&r1);
                pa.u[jj] = u0;
                pb.u[jj] = u1;
                // psum accumulates the ROUNDED values (num/denom consistent)
                s0 += __uint_as_float(u0 << 16) + __uint_as_float(u0 & 0xFFFF0000u);
                s1 += __uint_as_float(u1 << 16) + __uint_as_float(u1 & 0xFFFF0000u);
            }
            psum0 += s0;
            psum1 += s1;
            af0[kc] = pa.v;
            af1[kc] = pb.v;
        }

        // kc loop: bf double-buffered one step ahead, 16 MFMAs per kc
        #pragma unroll
        for (int kc = 0; kc < 4; ++kc) {
            bh8 bfB[8];
            if (kc < 3) loadB(bfB, hB, lr, kb + (kc + 1) * 32);
            #pragma unroll
            for (int ct = 0; ct < 8; ++ct) {
                acc0[ct] = __builtin_amdgcn_mfma_f32_16x16x32_bf16(af0[kc], bfA[ct], acc0[ct], 0, 0, 0);
                acc1[ct] = __builtin_amdgcn_mfma_f32_16x16x32_bf16(af1[kc], bfA[ct], acc1[ct], 0, 0, 0);
            }
            if (kc < 3) {
                #pragma unroll
                for (int ct = 0; ct < 8; ++ct) bfA[ct] = bfB[ct];
            }
        }
    }

    // psum: partials for rows lr / 16+lr live in lanes {lr, lr+16, lr+32, lr+48}
    psum0 += __shfl_xor(psum0, 16, 64);
    psum0 += __shfl_xor(psum0, 32, 64);
    psum1 += __shfl_xor(psum1, 16, 64);
    psum1 += __shfl_xor(psum1, 32, 64);
    if (lane < 16) {
        psum_sh[w][lr] = psum0;
        psum_sh[w][16 + lr] = psum1;
    }

    // C/D layout: col = ct*16 + (lane&15), row = (lane>>4)*4 + reg  [m89/m91]
    #pragma unroll
    for (int ct = 0; ct < 8; ++ct)
        #pragma unroll
        for (int reg = 0; reg < 4; ++reg) {
            accbuf[w][g * 4 + reg][ct * 16 + lr]      = acc0[ct][reg];
            accbuf[w][16 + g * 4 + reg][ct * 16 + lr] = acc1[ct][reg];
        }
    __syncthreads();

    // epilogue: sum 4 wave-partials, scale, write. 1024 float4 / 256 threads.
    #pragma unroll
    for (int rep = 0; rep < 4; ++rep) {
        const int idx = t + 256 * rep;
        const int r = idx >> 5;
        const int c4 = (idx & 31) * 4;
        const float4 s0 = *(const float4*)&accbuf[0][r][c4];
        const float4 s1 = *(const float4*)&accbuf[1][r][c4];
        const float4 s2 = *(const float4*)&accbuf[2][r][c4];
        const float4 s3 = *(const float4*)&accbuf[3][r][c4];
        const float ps = psum_sh[0][r] + psum_sh[1][r] + psum_sh[2][r] + psum_sh[3][r];
        const float sc = mask[b * NN + n0 + r] / ps;
        float4 o;
        o.x = (s0.x + s1.x + s2.x + s3.x) * sc;
        o.y = (s0.y + s1.y + s2.y + s3.y) * sc;
        o.z = (s0.z + s1.z + s2.z + s3.z) * sc;
        o.w = (s0.w + s1.w + s2.w + s3.w) * sc;
        *(float4*)&out[((long)b * NN + n0 + r) * FF + c4] = o;
    }
}

// ---------------------------------------------------------------------------
extern "C" void kernel_launch(void* const* d_in, const int* in_sizes, int n_in,
                              void* d_out, int out_size, void* d_ws, size_t ws_size,
                              hipStream_t stream)
{
    const float* feat = (const float*)d_in[0];
    const int*   adj  = (const int*)d_in[1];
    const float* mask = (const float*)d_in[2];
    const float* W    = (const float*)d_in[3];
    const float* bias = (const float*)d_in[4];
    const float* a    = (const float*)d_in[5];
    float* out = (float*)d_out;

    // ws: htg bf16 [8][128][2048] | esrc | edst | eed | eed2 (f32, 64KB each) | bm 4MB
    u16*   htg  = (u16*)d_ws;
    float* esrc = (float*)(htg + (size_t)BB * FF * NN);
    float* edst = esrc + BB * NN;
    float* eed  = edst + BB * NN;
    float* eed2 = eed + BB * NN;
    u64*   bmp  = (u64*)(eed2 + BB * NN);

    k_pack<<<BB * NN * NN / 64 / 256, 256, 0, stream>>>(adj, bmp);
    k_h   <<<BB * NN / 8, 256, 0, stream>>>(feat, W, bias, a, htg, esrc, edst, eed, eed2);
    k_attn<<<BB * (NN / RB), 256, 0, stream>>>(bmp, mask, htg, esrc, edst, eed, eed2, out);
}